// Round 4
// baseline (626.584 us; speedup 1.0000x reference)
//
#include <hip/hip_runtime.h>

// HyperbolicGraphPooling: out[g,:] = sum_{i: batch[i]==g} f[i,:] * sigmoid(f[i,:]@W + b)
// N=500000, C=256, G=2048, batch sorted ascending.
//
// R4: segment-per-block (2048 blocks = 8/CU exactly), 4 waves split the
// segment into contiguous quarters. Within a wave, lanes are partitioned into
// 4 groups of 16; group handles one row, lane owns 16 channels of that row.
// One 4-step shfl_xor butterfly reduces all 4 row-dots simultaneously
// (vs 24 shuffles/4 rows in R3), sigmoid once per lane. Manual 2-stage
// software pipeline keeps 8 loads in flight. Epilogue: 16 partial vectors
// (4 waves x 4 groups) reduced through a 16KB LDS tile, single coalesced
// store of out[g,:]. No atomics, no memset. Non-temporal feature loads.

constexpr int kChannels  = 256;
constexpr int kVecPerRow = kChannels / 4;  // 64 float4 per row

typedef float vfloat4 __attribute__((ext_vector_type(4)));

__device__ inline int lower_bound_i32(const int* __restrict__ b, int n, int v) {
    int lo = 0, hi = n;
    while (lo < hi) {
        int mid = (lo + hi) >> 1;
        if (b[mid] < v) lo = mid + 1; else hi = mid;
    }
    return lo;
}

__device__ inline float sigmoidf(float x) { return 1.0f / (1.0f + __expf(-x)); }

__device__ inline float dot4(vfloat4 a, vfloat4 b) {
    return a[0] * b[0] + a[1] * b[1] + a[2] * b[2] + a[3] * b[3];
}

__global__ __launch_bounds__(256, 2)
void hgp_seg_kernel(const float* __restrict__ features,
                    const int*   __restrict__ batch,
                    const float* __restrict__ W_att,
                    const float* __restrict__ b_att,
                    float*       __restrict__ out,
                    int n_nodes) {
    const int g    = blockIdx.x;          // segment id
    const int wv   = threadIdx.x >> 6;    // wave 0..3
    const int lane = threadIdx.x & 63;
    const int sub  = lane & 15;           // position within 16-lane group
    const int grp  = lane >> 4;           // which row of the 4 this lane handles

    const int seg_start = lower_bound_i32(batch, n_nodes, g);
    const int seg_end   = lower_bound_i32(batch, n_nodes, g + 1);
    const int seg_len   = seg_end - seg_start;

    // Wave's contiguous quarter of the segment.
    const int q   = (seg_len + 3) >> 2;
    const int ws_ = seg_start + wv * q;
    const int we_ = min(ws_ + q, seg_end);

    const vfloat4* __restrict__ frow = reinterpret_cast<const vfloat4*>(features);
    const vfloat4* __restrict__ W4   = reinterpret_cast<const vfloat4*>(W_att);

    // Lane's W fragment: channels {4*(sub+16j) .. +3}, j=0..3.
    const vfloat4 w0 = W4[sub];
    const vfloat4 w1 = W4[sub + 16];
    const vfloat4 w2 = W4[sub + 32];
    const vfloat4 w3 = W4[sub + 48];
    const float bias = b_att[0];

    vfloat4 a0 = 0.f, a1 = 0.f, a2 = 0.f, a3 = 0.f;

    int n = ws_;
    vfloat4 c0, c1, c2, c3;

    if (n + 4 <= we_) {
        const size_t rb = (size_t)(n + grp) * kVecPerRow + sub;
        c0 = __builtin_nontemporal_load(&frow[rb]);
        c1 = __builtin_nontemporal_load(&frow[rb + 16]);
        c2 = __builtin_nontemporal_load(&frow[rb + 32]);
        c3 = __builtin_nontemporal_load(&frow[rb + 48]);
    }

    for (; n + 8 <= we_; n += 4) {
        // Issue next 4-row loads before touching current data.
        const size_t rb = (size_t)(n + 4 + grp) * kVecPerRow + sub;
        vfloat4 x0 = __builtin_nontemporal_load(&frow[rb]);
        vfloat4 x1 = __builtin_nontemporal_load(&frow[rb + 16]);
        vfloat4 x2 = __builtin_nontemporal_load(&frow[rb + 32]);
        vfloat4 x3 = __builtin_nontemporal_load(&frow[rb + 48]);

        float p = dot4(c0, w0) + dot4(c1, w1) + dot4(c2, w2) + dot4(c3, w3);
        p += __shfl_xor(p, 8, 64);
        p += __shfl_xor(p, 4, 64);
        p += __shfl_xor(p, 2, 64);
        p += __shfl_xor(p, 1, 64);
        const float gate = sigmoidf(p + bias);

        a0 += c0 * gate; a1 += c1 * gate; a2 += c2 * gate; a3 += c3 * gate;

        c0 = x0; c1 = x1; c2 = x2; c3 = x3;
    }

    if (n + 4 <= we_) {  // drain the pipelined iteration
        float p = dot4(c0, w0) + dot4(c1, w1) + dot4(c2, w2) + dot4(c3, w3);
        p += __shfl_xor(p, 8, 64);
        p += __shfl_xor(p, 4, 64);
        p += __shfl_xor(p, 2, 64);
        p += __shfl_xor(p, 1, 64);
        const float gate = sigmoidf(p + bias);
        a0 += c0 * gate; a1 += c1 * gate; a2 += c2 * gate; a3 += c3 * gate;
        n += 4;
    }

    if (n < we_) {  // masked tail: 1..3 rows; out-of-range groups contribute 0
        const int  row = n + grp;
        const bool ok  = row < we_;
        const size_t rb = (size_t)(ok ? row : we_ - 1) * kVecPerRow + sub;
        vfloat4 t0 = __builtin_nontemporal_load(&frow[rb]);
        vfloat4 t1 = __builtin_nontemporal_load(&frow[rb + 16]);
        vfloat4 t2 = __builtin_nontemporal_load(&frow[rb + 32]);
        vfloat4 t3 = __builtin_nontemporal_load(&frow[rb + 48]);
        if (!ok) { t0 = 0.f; t1 = 0.f; t2 = 0.f; t3 = 0.f; }

        float p = dot4(t0, w0) + dot4(t1, w1) + dot4(t2, w2) + dot4(t3, w3);
        p += __shfl_xor(p, 8, 64);
        p += __shfl_xor(p, 4, 64);
        p += __shfl_xor(p, 2, 64);
        p += __shfl_xor(p, 1, 64);
        const float gate = sigmoidf(p + bias);
        a0 += t0 * gate; a1 += t1 * gate; a2 += t2 * gate; a3 += t3 * gate;
    }

    // 16 partial channel-vectors (4 waves x 4 groups) -> LDS -> one store.
    __shared__ float lds[16][kChannels];  // 16 KB
    {
        const int slot = wv * 4 + grp;
        vfloat4* dst = reinterpret_cast<vfloat4*>(lds[slot]);
        dst[sub]      = a0;
        dst[sub + 16] = a1;
        dst[sub + 32] = a2;
        dst[sub + 48] = a3;
    }
    __syncthreads();

    const int t = threadIdx.x;  // 0..255 == channel
    float s = 0.f;
    #pragma unroll
    for (int k = 0; k < 16; ++k) s += lds[k][t];
    out[(size_t)g * kChannels + t] = s;
}

extern "C" void kernel_launch(void* const* d_in, const int* in_sizes, int n_in,
                              void* d_out, int out_size, void* d_ws, size_t ws_size,
                              hipStream_t stream) {
    const float* features = (const float*)d_in[0];
    const int*   batch    = (const int*)d_in[1];
    const float* W_att    = (const float*)d_in[2];
    const float* b_att    = (const float*)d_in[3];
    float*       out      = (float*)d_out;

    const int n_nodes    = in_sizes[1];          // one batch entry per node
    const int num_graphs = out_size / kChannels; // 2048

    // Every out element written unconditionally (empty segments write 0):
    // no memset needed despite the 0xAA poison.
    hgp_seg_kernel<<<num_graphs, 256, 0, stream>>>(features, batch, W_att, b_att,
                                                   out, n_nodes);
}

// Round 5
// 619.882 us; speedup vs baseline: 1.0108x; 1.0108x over previous
//
#include <hip/hip_runtime.h>

// HyperbolicGraphPooling: out[g,:] = sum_{i: batch[i]==g} f[i,:] * sigmoid(f[i,:]@W + b)
// N=500000, C=256, G=2048, batch sorted ascending.
//
// R5: two-kernel plan.
//  K1: seg_bounds — one pass over batch writes offs[0..G] (2049 ints) to d_ws,
//      so the main kernel's startup is 2 scalar loads, not 2 binary searches
//      (~38 dependent global loads/block in R4).
//  K2: segment-per-block (2048 blocks), 4 waves x contiguous quarters. Lanes
//      split 4 groups x 16; group handles one row, lane owns 16 channels.
//      One 4-step shfl_xor butterfly reduces 4 row-dots at once. 3-stage
//      software pipeline: 12 x 1KB nontemporal loads in flight per wave.
//      LDS cross-wave reduce, single coalesced store. No atomics, no memset.

constexpr int kChannels  = 256;
constexpr int kVecPerRow = kChannels / 4;  // 64 float4 per row

typedef float vfloat4 __attribute__((ext_vector_type(4)));

__device__ inline float sigmoidf(float x) { return 1.0f / (1.0f + __expf(-x)); }

__device__ inline float dot4(vfloat4 a, vfloat4 b) {
    return a[0] * b[0] + a[1] * b[1] + a[2] * b[2] + a[3] * b[3];
}

__global__ void seg_bounds_kernel(const int* __restrict__ batch,
                                  int* __restrict__ offs,
                                  int n_nodes, int num_graphs) {
    const int i = blockIdx.x * blockDim.x + threadIdx.x;
    if (i >= n_nodes) return;
    const int b    = batch[i];
    const int prev = (i == 0) ? -1 : batch[i - 1];
    for (int v = prev + 1; v <= b; ++v) offs[v] = i;       // first index of seg v
    if (i == n_nodes - 1) {
        for (int v = b + 1; v <= num_graphs; ++v) offs[v] = n_nodes;
    }
}

__global__ __launch_bounds__(256, 2)
void hgp_seg_kernel(const float* __restrict__ features,
                    const int*   __restrict__ offs,
                    const float* __restrict__ W_att,
                    const float* __restrict__ b_att,
                    float*       __restrict__ out) {
    const int g    = blockIdx.x;          // segment id
    const int wv   = threadIdx.x >> 6;    // wave 0..3
    const int lane = threadIdx.x & 63;
    const int sub  = lane & 15;           // position within 16-lane group
    const int grp  = lane >> 4;           // which of the 4 rows this lane handles

    const int seg_start = offs[g];
    const int seg_end   = offs[g + 1];
    const int seg_len   = seg_end - seg_start;

    // Wave's contiguous quarter of the segment.
    const int q   = (seg_len + 3) >> 2;
    const int ws_ = seg_start + wv * q;
    const int we_ = min(ws_ + q, seg_end);

    const vfloat4* __restrict__ frow = reinterpret_cast<const vfloat4*>(features);
    const vfloat4* __restrict__ W4   = reinterpret_cast<const vfloat4*>(W_att);

    // Lane's W fragment: channels {4*(sub+16j) .. +3}, j=0..3.
    const vfloat4 w0 = W4[sub];
    const vfloat4 w1 = W4[sub + 16];
    const vfloat4 w2 = W4[sub + 32];
    const vfloat4 w3 = W4[sub + 48];
    const float bias = b_att[0];

    vfloat4 acc0 = 0.f, acc1 = 0.f, acc2 = 0.f, acc3 = 0.f;

    int n = ws_;
    // 3-stage pipeline buffers (stage = 4 rows; this wave's lane reads 4x16B).
    vfloat4 a0, a1, a2, a3;   // rows n .. n+3
    vfloat4 b0, b1, b2, b3;   // rows n+4 .. n+7

    if (n + 4 <= we_) {
        const size_t rb = (size_t)(n + grp) * kVecPerRow + sub;
        a0 = __builtin_nontemporal_load(&frow[rb]);
        a1 = __builtin_nontemporal_load(&frow[rb + 16]);
        a2 = __builtin_nontemporal_load(&frow[rb + 32]);
        a3 = __builtin_nontemporal_load(&frow[rb + 48]);
    }
    if (n + 8 <= we_) {
        const size_t rb = (size_t)(n + 4 + grp) * kVecPerRow + sub;
        b0 = __builtin_nontemporal_load(&frow[rb]);
        b1 = __builtin_nontemporal_load(&frow[rb + 16]);
        b2 = __builtin_nontemporal_load(&frow[rb + 32]);
        b3 = __builtin_nontemporal_load(&frow[rb + 48]);
    }

    #define HGP_COMPUTE(r0, r1, r2, r3)                                        \
        do {                                                                   \
            float p = dot4(r0, w0) + dot4(r1, w1) + dot4(r2, w2) + dot4(r3, w3); \
            p += __shfl_xor(p, 8, 64);                                         \
            p += __shfl_xor(p, 4, 64);                                         \
            p += __shfl_xor(p, 2, 64);                                         \
            p += __shfl_xor(p, 1, 64);                                         \
            const float gate = sigmoidf(p + bias);                             \
            acc0 += r0 * gate; acc1 += r1 * gate;                              \
            acc2 += r2 * gate; acc3 += r3 * gate;                              \
        } while (0)

    for (; n + 12 <= we_; n += 4) {
        // Issue stage-3 loads (rows n+8..n+11) before consuming stage-1.
        const size_t rb = (size_t)(n + 8 + grp) * kVecPerRow + sub;
        vfloat4 c0 = __builtin_nontemporal_load(&frow[rb]);
        vfloat4 c1 = __builtin_nontemporal_load(&frow[rb + 16]);
        vfloat4 c2 = __builtin_nontemporal_load(&frow[rb + 32]);
        vfloat4 c3 = __builtin_nontemporal_load(&frow[rb + 48]);

        HGP_COMPUTE(a0, a1, a2, a3);

        a0 = b0; a1 = b1; a2 = b2; a3 = b3;
        b0 = c0; b1 = c1; b2 = c2; b3 = c3;
    }

    if (n + 4 <= we_) {  // drain stage 1
        HGP_COMPUTE(a0, a1, a2, a3);
        n += 4;
        a0 = b0; a1 = b1; a2 = b2; a3 = b3;
    }
    if (n + 4 <= we_) {  // drain stage 2
        HGP_COMPUTE(a0, a1, a2, a3);
        n += 4;
    }

    if (n < we_) {  // masked tail: 1..3 rows; out-of-range groups contribute 0
        const int  row = n + grp;
        const bool ok  = row < we_;
        const size_t rb = (size_t)(ok ? row : we_ - 1) * kVecPerRow + sub;
        vfloat4 t0 = __builtin_nontemporal_load(&frow[rb]);
        vfloat4 t1 = __builtin_nontemporal_load(&frow[rb + 16]);
        vfloat4 t2 = __builtin_nontemporal_load(&frow[rb + 32]);
        vfloat4 t3 = __builtin_nontemporal_load(&frow[rb + 48]);
        if (!ok) { t0 = 0.f; t1 = 0.f; t2 = 0.f; t3 = 0.f; }
        HGP_COMPUTE(t0, t1, t2, t3);
    }
    #undef HGP_COMPUTE

    // 16 partial channel-vectors (4 waves x 4 groups) -> LDS -> one store.
    __shared__ float lds[16][kChannels];  // 16 KB
    {
        const int slot = wv * 4 + grp;
        vfloat4* dst = reinterpret_cast<vfloat4*>(lds[slot]);
        dst[sub]      = acc0;
        dst[sub + 16] = acc1;
        dst[sub + 32] = acc2;
        dst[sub + 48] = acc3;
    }
    __syncthreads();

    const int t = threadIdx.x;  // 0..255 == channel
    float s = 0.f;
    #pragma unroll
    for (int k = 0; k < 16; ++k) s += lds[k][t];
    out[(size_t)g * kChannels + t] = s;
}

extern "C" void kernel_launch(void* const* d_in, const int* in_sizes, int n_in,
                              void* d_out, int out_size, void* d_ws, size_t ws_size,
                              hipStream_t stream) {
    const float* features = (const float*)d_in[0];
    const int*   batch    = (const int*)d_in[1];
    const float* W_att    = (const float*)d_in[2];
    const float* b_att    = (const float*)d_in[3];
    float*       out      = (float*)d_out;
    int*         offs     = (int*)d_ws;          // 2049 ints of scratch

    const int n_nodes    = in_sizes[1];          // one batch entry per node
    const int num_graphs = out_size / kChannels; // 2048

    const int b1 = (n_nodes + 255) / 256;
    seg_bounds_kernel<<<b1, 256, 0, stream>>>(batch, offs, n_nodes, num_graphs);

    // Every out element written unconditionally (empty segments write 0):
    // no memset needed despite the 0xAA poison.
    hgp_seg_kernel<<<num_graphs, 256, 0, stream>>>(features, offs, W_att, b_att, out);
}